// Round 2
// baseline (622.168 us; speedup 1.0000x reference)
//
#include <hip/hip_runtime.h>

// B=2, N=2048, E=2048, H=16, D=128.
// Pipeline: merged cast fp32->bf16, q = x@Wq^T, kv = x@Wkv^T (bf16),
// V-transpose (per-batch [E][N], aliases dead xb), flash attention
// (barrier-free waves, K/V fragments direct from global), out = y@Wout^T (fp32).

typedef __bf16 bf16;
typedef bf16 bf16x8 __attribute__((ext_vector_type(8)));
typedef float f32x4 __attribute__((ext_vector_type(4)));

typedef const __attribute__((address_space(1))) void cg_void;
typedef __attribute__((address_space(3))) void lds_void;

#define MFMA16(a, b, c) __builtin_amdgcn_mfma_f32_16x16x32_bf16((a), (b), (c), 0, 0, 0)

__device__ __forceinline__ void async_load16(const bf16* g, bf16* l) {
  __builtin_amdgcn_global_load_lds((cg_void*)g, (lds_void*)l, 16, 0, 0);
}

// ---------------- merged cast fp32 -> bf16 (one launch for all 4 tensors) ----
__global__ __launch_bounds__(256) void cast_all_kernel(
    const float* __restrict__ x, const float* __restrict__ wq,
    const float* __restrict__ wkv, const float* __restrict__ wout,
    bf16* __restrict__ xb, bf16* __restrict__ wqb,
    bf16* __restrict__ wkvb, bf16* __restrict__ woutb) {
  long i = (long)blockIdx.x * 256 + threadIdx.x;  // 8-elem chunks
  const float* src; bf16* dst; long off;
  if (i < 1048576)      { src = x;    dst = xb;    off = i; }
  else if (i < 1572864) { src = wq;   dst = wqb;   off = i - 1048576; }
  else if (i < 2621440) { src = wkv;  dst = wkvb;  off = i - 1572864; }
  else                  { src = wout; dst = woutb; off = i - 2621440; }
  float4 f0 = ((const float4*)src)[2 * off];
  float4 f1 = ((const float4*)src)[2 * off + 1];
  bf16x8 o;
  o[0] = (bf16)f0.x; o[1] = (bf16)f0.y; o[2] = (bf16)f0.z; o[3] = (bf16)f0.w;
  o[4] = (bf16)f1.x; o[5] = (bf16)f1.y; o[6] = (bf16)f1.z; o[7] = (bf16)f1.w;
  ((bf16x8*)dst)[off] = o;
}

// ---------------- C[M,N] = A[M,K] * B[N,K]^T  (m97 structure, unchanged) ----
template <typename OutT>
__global__ __launch_bounds__(256, 2)
void gemm_bt_kernel(const bf16* __restrict__ A, const bf16* __restrict__ B,
                    OutT* __restrict__ C, int K, int NN) {
  __shared__ __attribute__((aligned(16))) bf16 As[128 * 32];
  __shared__ __attribute__((aligned(16))) bf16 Bs[128 * 32];
  const int tid = threadIdx.x;
  const int wave = tid >> 6, lane = tid & 63;
  const int quad = lane >> 4, l15 = lane & 15;
  const int m0 = blockIdx.y * 128, n0 = blockIdx.x * 128;
  const int wm = (wave >> 1) * 64, wn = (wave & 1) * 64;

  f32x4 acc[4][4];
#pragma unroll
  for (int i = 0; i < 4; ++i)
#pragma unroll
    for (int j = 0; j < 4; ++j) acc[i][j] = {0.f, 0.f, 0.f, 0.f};

  const int srow = tid >> 2;
  const int scol = (tid & 3) * 8;
  const bf16* aG = A + (size_t)(m0 + srow) * K + scol;
  const bf16* bG = B + (size_t)(n0 + srow) * K + scol;
  bf16* aL = As + srow * 32 + scol;
  bf16* bL = Bs + srow * 32 + scol;
  const size_t gstep = (size_t)64 * K;

  for (int kt = 0; kt < K; kt += 32) {
    __syncthreads();
    async_load16(aG, aL);
    async_load16(aG + gstep, aL + 64 * 32);
    async_load16(bG, bL);
    async_load16(bG + gstep, bL + 64 * 32);
    aG += 32; bG += 32;
    __syncthreads();

    bf16x8 af[4], bfr[4];
#pragma unroll
    for (int i = 0; i < 4; ++i)
      af[i] = *(const bf16x8*)(As + (wm + i * 16 + l15) * 32 + quad * 8);
#pragma unroll
    for (int j = 0; j < 4; ++j)
      bfr[j] = *(const bf16x8*)(Bs + (wn + j * 16 + l15) * 32 + quad * 8);
#pragma unroll
    for (int i = 0; i < 4; ++i)
#pragma unroll
      for (int j = 0; j < 4; ++j) acc[i][j] = MFMA16(af[i], bfr[j], acc[i][j]);
  }

#pragma unroll
  for (int i = 0; i < 4; ++i) {
#pragma unroll
    for (int r = 0; r < 4; ++r) {
      int row = m0 + wm + i * 16 + quad * 4 + r;
      size_t base = (size_t)row * NN + n0 + wn + l15;
#pragma unroll
      for (int j = 0; j < 4; ++j) C[base + j * 16] = (OutT)acc[i][j][r];
    }
  }
}

// ---------------- V transpose: kv V-half [b,n,f] -> Vt [b,f,n] ----------------
// 64x64 tiles, XOR-rotated LDS chunks (16B-aligned stores, spread reads).
__global__ __launch_bounds__(256) void vtrans_kernel(const bf16* __restrict__ kvb,
                                                     bf16* __restrict__ vt) {
  constexpr int KV = 4096, NSEQ = 2048, E = 2048;
  __shared__ __attribute__((aligned(16))) bf16 Ts[64 * 64];
  const int t = threadIdx.x;
  const int n0 = blockIdx.x * 64, f0 = blockIdx.y * 64, bb = blockIdx.z;
#pragma unroll
  for (int p = 0; p < 2; ++p) {
    int c = p * 256 + t;
    int i = c >> 3, jc = c & 7;
    bf16x8 v = *(const bf16x8*)(kvb + (size_t)(bb * NSEQ + n0 + i) * KV + E + f0 + jc * 8);
    *(bf16x8*)(Ts + i * 64 + ((jc + i) & 7) * 8) = v;  // rotate chunk by row
  }
  __syncthreads();
#pragma unroll
  for (int p = 0; p < 2; ++p) {
    int c = p * 256 + t;
    int fl = c >> 3, nl = (c & 7) * 8;
    bf16x8 o;
#pragma unroll
    for (int k = 0; k < 8; ++k) {
      int row = nl + k;
      o[k] = Ts[row * 64 + (((fl >> 3) + row) & 7) * 8 + (fl & 7)];
    }
    *(bf16x8*)(vt + (size_t)(bb * E + f0 + fl) * NSEQ + n0 + nl) = o;
  }
}

// ---------------- flash attention, causal, barrier-free -----------------------
// grid = (16, B*H). Block qt-pair (blockIdx.x, 31-blockIdx.x): every block does
// exactly 33 K-tile iterations -> perfect balance, all 512 blocks co-resident.
// 4 waves/block, wave = one 16-row m-tile; NO __syncthreads anywhere.
// K fragments: direct global from kv (row-major, token rows). V fragments:
// direct global from pre-transposed Vt. P: per-wave LDS round trip (m120).
__global__ __launch_bounds__(256, 2)
void attn_kernel(const bf16* __restrict__ qb, const bf16* __restrict__ kvb,
                 const bf16* __restrict__ vt, bf16* __restrict__ yb) {
  constexpr int NSEQ = 2048, E = 2048, KV = 4096;
  constexpr int PSTR = 72;
  __shared__ __attribute__((aligned(16))) bf16 PsAll[4][16 * PSTR];
  const int tid = threadIdx.x;
  const int wave = tid >> 6, lane = tid & 63;
  const int quad = lane >> 4, l15 = lane & 15;
  const int b = blockIdx.y >> 4, h = blockIdx.y & 15;
  const float scale = 0.08838834764831845f;  // 1/sqrt(128)
  bf16* ps = PsAll[wave];

  // lane-resolved base pointers (K: row=token l15, +quad*8 in k-dim;
  // Vt: row = feature h*128+l15, +quad*8 in token-dim)
  const bf16* kbase = kvb + (size_t)(b * NSEQ + l15) * KV + h * 128 + quad * 8;
  const bf16* vbase = vt + ((size_t)b * E + h * 128 + l15) * NSEQ + quad * 8;

  for (int phase = 0; phase < 2; ++phase) {
    const int qt = phase ? (31 - (int)blockIdx.x) : (int)blockIdx.x;
    const int r0 = qt * 64 + wave * 16;

    bf16x8 aq[4];
    {
      const bf16* qrow = qb + (size_t)(b * NSEQ + r0 + l15) * E + h * 128 + quad * 8;
#pragma unroll
      for (int ks = 0; ks < 4; ++ks) aq[ks] = *(const bf16x8*)(qrow + ks * 32);
    }

    float m_i[4], l_i[4], alpha[4];
    f32x4 accO[8];
#pragma unroll
    for (int r = 0; r < 4; ++r) { m_i[r] = -1e30f; l_i[r] = 0.f; }
#pragma unroll
    for (int dt = 0; dt < 8; ++dt) accO[dt] = {0.f, 0.f, 0.f, 0.f};

    for (int kt = 0; kt <= qt; ++kt) {
      // ---- S = Q K^T (16x64), K fragments straight from global ----
      const bf16* kp = kbase + (size_t)kt * 64 * KV;
      f32x4 s_acc[4];
#pragma unroll
      for (int j = 0; j < 4; ++j) s_acc[j] = {0.f, 0.f, 0.f, 0.f};
#pragma unroll
      for (int j = 0; j < 4; ++j) {
        const bf16* kr = kp + (size_t)(j * 16) * KV;
#pragma unroll
        for (int ks = 0; ks < 4; ++ks) {
          bf16x8 bk = *(const bf16x8*)(kr + ks * 32);
          s_acc[j] = MFMA16(aq[ks], bk, s_acc[j]);
        }
      }

      // ---- online softmax; only the diagonal tile needs the causal mask ----
      const bool lastt = (kt == qt);
#pragma unroll
      for (int r = 0; r < 4; ++r) {
        float sv[4];
        if (lastt) {
          const int lrow = wave * 16 + quad * 4 + r;  // row within 64-tile
#pragma unroll
          for (int j = 0; j < 4; ++j) {
            int lcol = j * 16 + l15;
            float s = s_acc[j][r] * scale;
            sv[j] = (lcol > lrow) ? -1e30f : s;
          }
        } else {
#pragma unroll
          for (int j = 0; j < 4; ++j) sv[j] = s_acc[j][r] * scale;
        }
        float mx = fmaxf(fmaxf(sv[0], sv[1]), fmaxf(sv[2], sv[3]));
#pragma unroll
        for (int sh = 1; sh < 16; sh <<= 1) mx = fmaxf(mx, __shfl_xor(mx, sh));
        float mnew = fmaxf(m_i[r], mx);
        float a = __expf(m_i[r] - mnew);
        alpha[r] = a;
        m_i[r] = mnew;
        float psum = 0.f;
#pragma unroll
        for (int j = 0; j < 4; ++j) {
          float p = __expf(sv[j] - mnew);
          psum += p;
          ps[(quad * 4 + r) * PSTR + j * 16 + l15] = (bf16)p;
        }
#pragma unroll
        for (int sh = 1; sh < 16; sh <<= 1) psum += __shfl_xor(psum, sh);
        l_i[r] = l_i[r] * a + psum;
      }

      // ---- rescale O, then PV with V fragments straight from global Vt ----
#pragma unroll
      for (int dt = 0; dt < 8; ++dt) {
        f32x4 t = accO[dt];
        t[0] *= alpha[0]; t[1] *= alpha[1]; t[2] *= alpha[2]; t[3] *= alpha[3];
        accO[dt] = t;
      }
      const bf16* vp = vbase + kt * 64;
#pragma unroll
      for (int kk = 0; kk < 2; ++kk) {
        bf16x8 ap = *(const bf16x8*)(ps + l15 * PSTR + kk * 32 + quad * 8);
#pragma unroll
        for (int dt = 0; dt < 8; ++dt) {
          bf16x8 bv = *(const bf16x8*)(vp + (size_t)(dt * 16) * NSEQ + kk * 32);
          accO[dt] = MFMA16(ap, bv, accO[dt]);
        }
      }
    }

    // ---- normalize and write merged-head [B*N, E] bf16 ----
#pragma unroll
    for (int r = 0; r < 4; ++r) {
      float inv = 1.0f / l_i[r];
      size_t base = (size_t)(b * NSEQ + r0 + quad * 4 + r) * E + h * 128 + l15;
#pragma unroll
      for (int dt = 0; dt < 8; ++dt) yb[base + dt * 16] = (bf16)(accO[dt][r] * inv);
    }
  }
}

// ---------------- launch ----------------
extern "C" void kernel_launch(void* const* d_in, const int* in_sizes, int n_in,
                              void* d_out, int out_size, void* d_ws, size_t ws_size,
                              hipStream_t stream) {
  const float* x    = (const float*)d_in[0];
  const float* Wq   = (const float*)d_in[1];
  const float* Wkv  = (const float*)d_in[2];
  const float* Wout = (const float*)d_in[3];
  float* out = (float*)d_out;

  constexpr size_t NX = (size_t)2 * 2048 * 2048;  // 8388608
  constexpr size_t NW = (size_t)2048 * 2048;      // 4194304

  bf16* xb    = (bf16*)d_ws;
  bf16* wqb   = xb + NX;
  bf16* wkvb  = wqb + NW;
  bf16* woutb = wkvb + 2 * NW;
  bf16* q_b   = woutb + NW;
  bf16* kv_b  = q_b + NX;
  bf16* y_b   = kv_b + 2 * NX;
  bf16* vt_b  = xb;  // alias: xb dead after the two projection GEMMs; same size (B*E*N)

  cast_all_kernel<<<12288, 256, 0, stream>>>(x, Wq, Wkv, Wout, xb, wqb, wkvb, woutb);

  // q = x @ Wq^T : [4096,2048]
  gemm_bt_kernel<bf16><<<dim3(16, 32), 256, 0, stream>>>(xb, wqb, q_b, 2048, 2048);
  // kv = x @ Wkv^T : [4096,4096]
  gemm_bt_kernel<bf16><<<dim3(32, 32), 256, 0, stream>>>(xb, wkvb, kv_b, 2048, 4096);
  // V half of kv -> Vt [b, f, n]  (overwrites xb)
  vtrans_kernel<<<dim3(32, 32, 2), 256, 0, stream>>>(kv_b, vt_b);
  // attention -> y [4096,2048] bf16
  attn_kernel<<<dim3(16, 32), 256, 0, stream>>>(q_b, kv_b, vt_b, y_b);
  // out = y @ Wout^T : fp32
  gemm_bt_kernel<float><<<dim3(16, 32), 256, 0, stream>>>(y_b, woutb, out, 2048, 2048);
}

// Round 3
// 393.285 us; speedup vs baseline: 1.5820x; 1.5820x over previous
//
#include <hip/hip_runtime.h>

// B=2, N=2048, E=2048, H=16, D=128.
// Pipeline: cast fp32->bf16 (1 launch), qkv = x@[Wq;Wkv]^T (one fused GEMM,
// [4096 x 6144] bf16), V-transpose -> Vt[b][f][n], flash attention in S^T
// formulation (32x32x16 MFMA, LDS-staged K/V via global_load_lds + XOR swizzle,
// per-CU-balanced causal qt assignment), out = y@Wout^T (fp32).

typedef __bf16 bf16;
typedef bf16 bf16x4 __attribute__((ext_vector_type(4)));
typedef bf16 bf16x8 __attribute__((ext_vector_type(8)));
typedef float f32x4 __attribute__((ext_vector_type(4)));
typedef float f32x16 __attribute__((ext_vector_type(16)));

typedef const __attribute__((address_space(1))) void cg_void;
typedef __attribute__((address_space(3))) void lds_void;

#define MFMA16(a, b, c) __builtin_amdgcn_mfma_f32_16x16x32_bf16((a), (b), (c), 0, 0, 0)
#define MFMA32(a, b, c) __builtin_amdgcn_mfma_f32_32x32x16_bf16((a), (b), (c), 0, 0, 0)

__device__ __forceinline__ void async_load16(const bf16* g, bf16* l) {
  __builtin_amdgcn_global_load_lds((cg_void*)g, (lds_void*)l, 16, 0, 0);
}

// ---------------- merged cast fp32 -> bf16 ----------------
__global__ __launch_bounds__(256) void cast_all_kernel(
    const float* __restrict__ x, const float* __restrict__ wq,
    const float* __restrict__ wkv, const float* __restrict__ wout,
    bf16* __restrict__ xb, bf16* __restrict__ wqkvb, bf16* __restrict__ woutb) {
  long i = (long)blockIdx.x * 256 + threadIdx.x;  // 8-elem chunks
  const float* src; bf16* dst; long off;
  if (i < 1048576)      { src = x;    dst = xb;            off = i; }
  else if (i < 2621440) { src = wq;   dst = wqkvb;         off = i - 1048576;
                          if (off >= 524288) { src = wkv; dst = wqkvb + 4194304; off -= 524288; } }
  else                  { src = wout; dst = woutb;         off = i - 2621440; }
  float4 f0 = ((const float4*)src)[2 * off];
  float4 f1 = ((const float4*)src)[2 * off + 1];
  bf16x8 o;
  o[0] = (bf16)f0.x; o[1] = (bf16)f0.y; o[2] = (bf16)f0.z; o[3] = (bf16)f0.w;
  o[4] = (bf16)f1.x; o[5] = (bf16)f1.y; o[6] = (bf16)f1.z; o[7] = (bf16)f1.w;
  ((bf16x8*)dst)[off] = o;
}

// ---------------- C[M,N] = A[M,K] * B[N,K]^T  (m97 structure) ----------------
template <typename OutT>
__global__ __launch_bounds__(256, 2)
void gemm_bt_kernel(const bf16* __restrict__ A, const bf16* __restrict__ B,
                    OutT* __restrict__ C, int K, int NN) {
  __shared__ __attribute__((aligned(16))) bf16 As[128 * 32];
  __shared__ __attribute__((aligned(16))) bf16 Bs[128 * 32];
  const int tid = threadIdx.x;
  const int wave = tid >> 6, lane = tid & 63;
  const int quad = lane >> 4, l15 = lane & 15;
  const int m0 = blockIdx.y * 128, n0 = blockIdx.x * 128;
  const int wm = (wave >> 1) * 64, wn = (wave & 1) * 64;

  f32x4 acc[4][4];
#pragma unroll
  for (int i = 0; i < 4; ++i)
#pragma unroll
    for (int j = 0; j < 4; ++j) acc[i][j] = {0.f, 0.f, 0.f, 0.f};

  const int srow = tid >> 2;
  const int scol = (tid & 3) * 8;
  const bf16* aG = A + (size_t)(m0 + srow) * K + scol;
  const bf16* bG = B + (size_t)(n0 + srow) * K + scol;
  bf16* aL = As + srow * 32 + scol;
  bf16* bL = Bs + srow * 32 + scol;
  const size_t gstep = (size_t)64 * K;

  for (int kt = 0; kt < K; kt += 32) {
    __syncthreads();
    async_load16(aG, aL);
    async_load16(aG + gstep, aL + 64 * 32);
    async_load16(bG, bL);
    async_load16(bG + gstep, bL + 64 * 32);
    aG += 32; bG += 32;
    __syncthreads();

    bf16x8 af[4], bfr[4];
#pragma unroll
    for (int i = 0; i < 4; ++i)
      af[i] = *(const bf16x8*)(As + (wm + i * 16 + l15) * 32 + quad * 8);
#pragma unroll
    for (int j = 0; j < 4; ++j)
      bfr[j] = *(const bf16x8*)(Bs + (wn + j * 16 + l15) * 32 + quad * 8);
#pragma unroll
    for (int i = 0; i < 4; ++i)
#pragma unroll
      for (int j = 0; j < 4; ++j) acc[i][j] = MFMA16(af[i], bfr[j], acc[i][j]);
  }

#pragma unroll
  for (int i = 0; i < 4; ++i) {
#pragma unroll
    for (int r = 0; r < 4; ++r) {
      int row = m0 + wm + i * 16 + quad * 4 + r;
      size_t base = (size_t)row * NN + n0 + wn + l15;
#pragma unroll
      for (int j = 0; j < 4; ++j) C[base + j * 16] = (OutT)acc[i][j][r];
    }
  }
}

// ---------------- V transpose: qkv V-cols [b,n,4096+f] -> Vt [b,f,n] ----------
__global__ __launch_bounds__(256) void vtrans_kernel(const bf16* __restrict__ qkvb,
                                                     bf16* __restrict__ vt) {
  constexpr int QKV = 6144, NSEQ = 2048, E = 2048;
  __shared__ __attribute__((aligned(16))) bf16 Ts[64 * 64];
  const int t = threadIdx.x;
  const int n0 = blockIdx.x * 64, f0 = blockIdx.y * 64, bb = blockIdx.z;
#pragma unroll
  for (int p = 0; p < 2; ++p) {
    int c = p * 256 + t;
    int i = c >> 3, jc = c & 7;
    bf16x8 v = *(const bf16x8*)(qkvb + (size_t)(bb * NSEQ + n0 + i) * QKV + 4096 + f0 + jc * 8);
    *(bf16x8*)(Ts + i * 64 + ((jc + i) & 7) * 8) = v;  // rotate chunk by row
  }
  __syncthreads();
#pragma unroll
  for (int p = 0; p < 2; ++p) {
    int c = p * 256 + t;
    int fl = c >> 3, nl = (c & 7) * 8;
    bf16x8 o;
#pragma unroll
    for (int k = 0; k < 8; ++k) {
      int row = nl + k;
      o[k] = Ts[row * 64 + (((fl >> 3) + row) & 7) * 8 + (fl & 7)];
    }
    *(bf16x8*)(vt + (size_t)(bb * E + f0 + fl) * NSEQ + n0 + nl) = o;
  }
}

// ---------------- flash attention, causal, S^T formulation --------------------
// grid = (32 bh, 32 slot), 128 threads (2 waves), wave owns 32 q rows.
// qt from slot so each CU's 4 resident blocks sum to 66 iterations (balance
// heuristic; correctness independent). S^T = K*Q^T, O^T = V^T*P^T, 32x32x16.
// Lane owns q-column lane&31; softmax reductions in-lane + one shfl_xor(32).
// K/V staged to LDS via global_load_lds with XOR chunk swizzle (linear dest).
__global__ __launch_bounds__(128, 2)
void attn_kernel(const bf16* __restrict__ qkv, const bf16* __restrict__ vt,
                 bf16* __restrict__ yb) {
  constexpr int NSEQ = 2048, E = 2048, QKV = 6144;
  __shared__ __attribute__((aligned(16))) bf16 Ks[64 * 128];   // [tok][d], swizzled
  __shared__ __attribute__((aligned(16))) bf16 Vs[128 * 64];   // [d][tok], swizzled
  __shared__ __attribute__((aligned(16))) bf16 Ps[2][32 * 64]; // per-wave P^T [q][tok], swizzled
  const int tid = threadIdx.x;
  const int wave = tid >> 6, lane = tid & 63;
  const int l31 = lane & 31, half = lane >> 5;
  const int b = blockIdx.x >> 4, h = blockIdx.x & 15;
  const int slot = blockIdx.y, qsub = slot & 7, g = slot >> 3;
  const int qt = (g == 0) ? qsub : (g == 1) ? 15 - qsub : (g == 2) ? 16 + qsub : 31 - qsub;
  const float c1 = 0.08838834764831845f * 1.44269504088896f;  // scale * log2(e)

  const int qrow = qt * 64 + wave * 32 + l31;  // this lane's q column (global)
  bf16x8 qf[8];
  {
    const bf16* qp = qkv + (size_t)(b * NSEQ + qrow) * QKV + h * 128 + half * 8;
#pragma unroll
    for (int k8 = 0; k8 < 8; ++k8) qf[k8] = *(const bf16x8*)(qp + k8 * 16);
  }

  float m = -3.0e38f, l = 0.f;
  f32x16 accO[4];
#pragma unroll
  for (int md = 0; md < 4; ++md)
#pragma unroll
    for (int r = 0; r < 16; ++r) accO[md][r] = 0.f;

  bf16* psw = Ps[wave];
  const int ksr = tid >> 4, kss = tid & 15;  // K staging: row-in-call, dest chunk
  const int vsr = tid >> 3, vss = tid & 7;   // V staging
  bf16* kdst = Ks + tid * 8;
  bf16* vdst = Vs + tid * 8;

  for (int kt = 0; kt <= qt; ++kt) {
    __syncthreads();
#pragma unroll
    for (int p = 0; p < 8; ++p) {  // K tile: 64 rows x 128 d (16 chunks/row)
      int r = p * 8 + ksr;
      int gch = kss ^ (r & 7);
      const bf16* gsrc = qkv + (size_t)(b * NSEQ + kt * 64 + r) * QKV + 2048 + h * 128 + gch * 8;
      async_load16(gsrc, kdst + p * 1024);
    }
#pragma unroll
    for (int p = 0; p < 8; ++p) {  // V tile: 128 d-rows x 64 tok (8 chunks/row)
      int r = p * 16 + vsr;
      int gch = vss ^ (r & 7);
      const bf16* gsrc = vt + ((size_t)b * E + h * 128 + r) * NSEQ + kt * 64 + gch * 8;
      async_load16(gsrc, vdst + p * 1024);
    }
    __syncthreads();

    // ---- S^T = K * Q^T : two 32x32 tiles (tok x q) ----
    f32x16 st[2];
#pragma unroll
    for (int mt = 0; mt < 2; ++mt)
#pragma unroll
      for (int r = 0; r < 16; ++r) st[mt][r] = 0.f;
#pragma unroll
    for (int k8 = 0; k8 < 8; ++k8) {
#pragma unroll
      for (int mt = 0; mt < 2; ++mt) {
        int row = mt * 32 + l31;
        int sl = (k8 * 2 + half) ^ (row & 7);
        bf16x8 kf = *(const bf16x8*)(Ks + row * 128 + sl * 8);
        st[mt] = MFMA32(kf, qf[k8], st[mt]);
      }
    }

    // causal mask (diagonal tile only); C row = (reg&3)+8*(reg>>2)+4*half
    if (kt == qt) {
#pragma unroll
      for (int mt = 0; mt < 2; ++mt)
#pragma unroll
        for (int r = 0; r < 16; ++r) {
          int t = kt * 64 + mt * 32 + (r & 3) + 8 * (r >> 2) + 4 * half;
          if (t > qrow) st[mt][r] = -3.0e38f;
        }
    }

    // ---- online softmax: in-lane over 32 tokens + 1 shuffle across halves ----
    float mx = -3.0e38f;
#pragma unroll
    for (int mt = 0; mt < 2; ++mt)
#pragma unroll
      for (int r = 0; r < 16; ++r) mx = fmaxf(mx, st[mt][r]);
    mx = fmaxf(mx, __shfl_xor(mx, 32));
    float mnew = fmaxf(m, mx);
    float alpha = exp2f((m - mnew) * c1);
    float mc = mnew * c1;
    m = mnew;
    float psum = 0.f;
#pragma unroll
    for (int mt = 0; mt < 2; ++mt)
#pragma unroll
      for (int r = 0; r < 16; ++r) {
        float p = exp2f(st[mt][r] * c1 - mc);
        psum += p;
        int t = mt * 32 + (r & 3) + 8 * (r >> 2) + 4 * half;
        psw[l31 * 64 + ((t >> 3) ^ (l31 & 7)) * 8 + (t & 7)] = (bf16)p;
      }
    psum += __shfl_xor(psum, 32);
    l = l * alpha + psum;

    if (alpha != 1.0f) {  // skip rescale when no lane's max moved (execz branch)
#pragma unroll
      for (int md = 0; md < 4; ++md)
#pragma unroll
        for (int r = 0; r < 16; ++r) accO[md][r] *= alpha;
    }

    // ---- O^T += V^T * P^T ----
    bf16x8 pf[4];
#pragma unroll
    for (int kk = 0; kk < 4; ++kk) {
      int sl = (kk * 2 + half) ^ (l31 & 7);
      pf[kk] = *(const bf16x8*)(psw + l31 * 64 + sl * 8);
    }
#pragma unroll
    for (int md = 0; md < 4; ++md) {
      int row = md * 32 + l31;
#pragma unroll
      for (int kk = 0; kk < 4; ++kk) {
        int sl = (kk * 2 + half) ^ (row & 7);
        bf16x8 vf = *(const bf16x8*)(Vs + row * 64 + sl * 8);
        accO[md] = MFMA32(vf, pf[kk], accO[md]);
      }
    }
  }

  // ---- normalize, write y[b, q, h*128 + d] (lane = one q row; d packed x4) ----
  float invl = 1.0f / l;
  bf16* yp = yb + (size_t)(b * NSEQ + qrow) * E + h * 128;
#pragma unroll
  for (int md = 0; md < 4; ++md)
#pragma unroll
    for (int rq = 0; rq < 4; ++rq) {
      bf16x4 o;
#pragma unroll
      for (int i = 0; i < 4; ++i) o[i] = (bf16)(accO[md][rq * 4 + i] * invl);
      *(bf16x4*)(yp + md * 32 + rq * 8 + half * 4) = o;
    }
}

// ---------------- launch ----------------
extern "C" void kernel_launch(void* const* d_in, const int* in_sizes, int n_in,
                              void* d_out, int out_size, void* d_ws, size_t ws_size,
                              hipStream_t stream) {
  const float* x    = (const float*)d_in[0];
  const float* Wq   = (const float*)d_in[1];
  const float* Wkv  = (const float*)d_in[2];
  const float* Wout = (const float*)d_in[3];
  float* out = (float*)d_out;

  constexpr size_t NX = (size_t)2 * 2048 * 2048;  // 8388608
  constexpr size_t NW = (size_t)2048 * 2048;      // 4194304

  bf16* xb     = (bf16*)d_ws;
  bf16* wqkvb  = xb + NX;          // [6144 x 2048] = Wq rows then Wkv rows
  bf16* woutb  = wqkvb + 3 * NW;
  bf16* qkv_b  = woutb + NW;       // [4096 x 6144]: q | k | v per row
  bf16* y_b    = qkv_b + 3 * NX;
  bf16* vt_b   = xb;               // alias: xb dead after qkv GEMM

  cast_all_kernel<<<12288, 256, 0, stream>>>(x, Wq, Wkv, Wout, xb, wqkvb, woutb);

  // qkv = x @ [Wq; Wkv]^T : [4096, 6144]
  gemm_bt_kernel<bf16><<<dim3(48, 32), 256, 0, stream>>>(xb, wqkvb, qkv_b, 2048, 6144);
  // V cols of qkv -> Vt [b, f, n] (overwrites xb)
  vtrans_kernel<<<dim3(32, 32, 2), 256, 0, stream>>>(qkv_b, vt_b);
  // attention -> y [4096, 2048] bf16
  attn_kernel<<<dim3(32, 32), 128, 0, stream>>>(qkv_b, vt_b, y_b);
  // out = y @ Wout^T : fp32
  gemm_bt_kernel<float><<<dim3(16, 32), 256, 0, stream>>>(y_b, woutb, out, 2048, 2048);
}

// Round 4
// 384.045 us; speedup vs baseline: 1.6200x; 1.0241x over previous
//
#include <hip/hip_runtime.h>

// B=2, N=2048, E=2048, H=16, D=128.
// Pipeline: cast fp32->bf16 (1 launch), qkv = x@[Wq;Wkv]^T (fused GEMM, bf16),
// V-transpose -> Vt[b][f][n], flash attention S^T formulation (32x32x16 MFMA,
// 128-row Q tiles, 4 waves, K/V LDS-staged via global_load_lds + XOR swizzle,
// P passed register-only via half-wave shfl_xor), out = y@Wout^T (fp32).

typedef __bf16 bf16;
typedef bf16 bf16x2 __attribute__((ext_vector_type(2)));
typedef bf16 bf16x4 __attribute__((ext_vector_type(4)));
typedef bf16 bf16x8 __attribute__((ext_vector_type(8)));
typedef float f32x4 __attribute__((ext_vector_type(4)));
typedef float f32x16 __attribute__((ext_vector_type(16)));

typedef const __attribute__((address_space(1))) void cg_void;
typedef __attribute__((address_space(3))) void lds_void;

#define MFMA16(a, b, c) __builtin_amdgcn_mfma_f32_16x16x32_bf16((a), (b), (c), 0, 0, 0)
#define MFMA32(a, b, c) __builtin_amdgcn_mfma_f32_32x32x16_bf16((a), (b), (c), 0, 0, 0)

__device__ __forceinline__ void async_load16(const bf16* g, bf16* l) {
  __builtin_amdgcn_global_load_lds((cg_void*)g, (lds_void*)l, 16, 0, 0);
}

// ---------------- merged cast fp32 -> bf16 ----------------
__global__ __launch_bounds__(256) void cast_all_kernel(
    const float* __restrict__ x, const float* __restrict__ wq,
    const float* __restrict__ wkv, const float* __restrict__ wout,
    bf16* __restrict__ xb, bf16* __restrict__ wqkvb, bf16* __restrict__ woutb) {
  long i = (long)blockIdx.x * 256 + threadIdx.x;  // 8-elem chunks
  const float* src; bf16* dst; long off;
  if (i < 1048576)      { src = x;    dst = xb;            off = i; }
  else if (i < 2621440) { src = wq;   dst = wqkvb;         off = i - 1048576;
                          if (off >= 524288) { src = wkv; dst = wqkvb + 4194304; off -= 524288; } }
  else                  { src = wout; dst = woutb;         off = i - 2621440; }
  float4 f0 = ((const float4*)src)[2 * off];
  float4 f1 = ((const float4*)src)[2 * off + 1];
  bf16x8 o;
  o[0] = (bf16)f0.x; o[1] = (bf16)f0.y; o[2] = (bf16)f0.z; o[3] = (bf16)f0.w;
  o[4] = (bf16)f1.x; o[5] = (bf16)f1.y; o[6] = (bf16)f1.z; o[7] = (bf16)f1.w;
  ((bf16x8*)dst)[off] = o;
}

// ---------------- C[M,N] = A[M,K] * B[N,K]^T  (m97 structure) ----------------
// launch_bounds(256,4): VGPR+AGPR ~120 fits the 128-reg/4-wave budget -> 4 blk/CU.
template <typename OutT>
__global__ __launch_bounds__(256, 4)
void gemm_bt_kernel(const bf16* __restrict__ A, const bf16* __restrict__ B,
                    OutT* __restrict__ C, int K, int NN) {
  __shared__ __attribute__((aligned(16))) bf16 As[128 * 32];
  __shared__ __attribute__((aligned(16))) bf16 Bs[128 * 32];
  const int tid = threadIdx.x;
  const int wave = tid >> 6, lane = tid & 63;
  const int quad = lane >> 4, l15 = lane & 15;
  const int m0 = blockIdx.y * 128, n0 = blockIdx.x * 128;
  const int wm = (wave >> 1) * 64, wn = (wave & 1) * 64;

  f32x4 acc[4][4];
#pragma unroll
  for (int i = 0; i < 4; ++i)
#pragma unroll
    for (int j = 0; j < 4; ++j) acc[i][j] = {0.f, 0.f, 0.f, 0.f};

  const int srow = tid >> 2;
  const int scol = (tid & 3) * 8;
  const bf16* aG = A + (size_t)(m0 + srow) * K + scol;
  const bf16* bG = B + (size_t)(n0 + srow) * K + scol;
  bf16* aL = As + srow * 32 + scol;
  bf16* bL = Bs + srow * 32 + scol;
  const size_t gstep = (size_t)64 * K;

  for (int kt = 0; kt < K; kt += 32) {
    __syncthreads();
    async_load16(aG, aL);
    async_load16(aG + gstep, aL + 64 * 32);
    async_load16(bG, bL);
    async_load16(bG + gstep, bL + 64 * 32);
    aG += 32; bG += 32;
    __syncthreads();

    bf16x8 af[4], bfr[4];
#pragma unroll
    for (int i = 0; i < 4; ++i)
      af[i] = *(const bf16x8*)(As + (wm + i * 16 + l15) * 32 + quad * 8);
#pragma unroll
    for (int j = 0; j < 4; ++j)
      bfr[j] = *(const bf16x8*)(Bs + (wn + j * 16 + l15) * 32 + quad * 8);
#pragma unroll
    for (int i = 0; i < 4; ++i)
#pragma unroll
      for (int j = 0; j < 4; ++j) acc[i][j] = MFMA16(af[i], bfr[j], acc[i][j]);
  }

#pragma unroll
  for (int i = 0; i < 4; ++i) {
#pragma unroll
    for (int r = 0; r < 4; ++r) {
      int row = m0 + wm + i * 16 + quad * 4 + r;
      size_t base = (size_t)row * NN + n0 + wn + l15;
#pragma unroll
      for (int j = 0; j < 4; ++j) C[base + j * 16] = (OutT)acc[i][j][r];
    }
  }
}

// ---------------- V transpose: qkv V-cols [b,n,4096+f] -> Vt [b,f,n] ----------
__global__ __launch_bounds__(256) void vtrans_kernel(const bf16* __restrict__ qkvb,
                                                     bf16* __restrict__ vt) {
  constexpr int QKV = 6144, NSEQ = 2048, E = 2048;
  __shared__ __attribute__((aligned(16))) bf16 Ts[64 * 64];
  const int t = threadIdx.x;
  const int n0 = blockIdx.x * 64, f0 = blockIdx.y * 64, bb = blockIdx.z;
#pragma unroll
  for (int p = 0; p < 2; ++p) {
    int c = p * 256 + t;
    int i = c >> 3, jc = c & 7;
    bf16x8 v = *(const bf16x8*)(qkvb + (size_t)(bb * NSEQ + n0 + i) * QKV + 4096 + f0 + jc * 8);
    *(bf16x8*)(Ts + i * 64 + ((jc + i) & 7) * 8) = v;  // rotate chunk by row
  }
  __syncthreads();
#pragma unroll
  for (int p = 0; p < 2; ++p) {
    int c = p * 256 + t;
    int fl = c >> 3, nl = (c & 7) * 8;
    bf16x8 o;
#pragma unroll
    for (int k = 0; k < 8; ++k) {
      int row = nl + k;
      o[k] = Ts[row * 64 + (((fl >> 3) + row) & 7) * 8 + (fl & 7)];
    }
    *(bf16x8*)(vt + (size_t)(bb * E + f0 + fl) * NSEQ + n0 + nl) = o;
  }
}

// ---------------- flash attention, causal, S^T formulation --------------------
// grid = (32 bh, 16 slot), 256 threads (4 waves). Q-tile = 128 rows; wave w owns
// rows qt*128 + w*32 + (lane&31). K/V tiles of 64 tokens staged to 32 KB LDS.
// qt = slot<8 ? slot : 23-slot (resident pairs id,id+256 sum to 34 iters).
// P^T never touches LDS: C-layout -> B-operand via packed-bf16 shfl_xor(32).
__global__ __launch_bounds__(256, 2)
void attn_kernel(const bf16* __restrict__ qkv, const bf16* __restrict__ vt,
                 bf16* __restrict__ yb) {
  constexpr int NSEQ = 2048, E = 2048, QKV = 6144;
  __shared__ __attribute__((aligned(16))) bf16 Ks[64 * 128];   // [tok][d], XOR-swizzled
  __shared__ __attribute__((aligned(16))) bf16 Vs[128 * 64];   // [d][tok], XOR-swizzled
  const int tid = threadIdx.x;
  const int wave = tid >> 6, lane = tid & 63;
  const int l31 = lane & 31, half = lane >> 5;
  const int b = blockIdx.x >> 4, h = blockIdx.x & 15;
  const int slot = blockIdx.y;
  const int qt = (slot < 8) ? slot : 23 - slot;
  const float c1 = 0.08838834764831845f * 1.44269504088896f;  // scale * log2(e)

  const int qrow = qt * 128 + wave * 32 + l31;  // this lane's q column (global)
  bf16x8 qf[8];
  {
    const bf16* qp = qkv + (size_t)(b * NSEQ + qrow) * QKV + h * 128 + half * 8;
#pragma unroll
    for (int k8 = 0; k8 < 8; ++k8) qf[k8] = *(const bf16x8*)(qp + k8 * 16);
  }

  float m = -3.0e38f, l = 0.f;
  f32x16 accO[4];
#pragma unroll
  for (int md = 0; md < 4; ++md)
#pragma unroll
    for (int r = 0; r < 16; ++r) accO[md][r] = 0.f;

  // staging geometry (256 threads)
  const int krow_s = tid >> 4, kch_s = tid & 15;  // K: 16 chunks/row, 16 rows/sweep
  const int vrow_s = tid >> 3, vch_s = tid & 7;   // V: 8 chunks/row, 32 rows/sweep
  bf16* kdst = Ks + tid * 8;
  bf16* vdst = Vs + tid * 8;

  const int diag = 2 * qt + (wave >> 1);  // this wave's diagonal 64-token tile
  const int ktmax = 2 * qt + 1;

  union PU { unsigned u; bf16x2 h; };
  union FU { bf16x8 v; unsigned u[4]; };

  for (int kt = 0; kt <= ktmax; ++kt) {
    __syncthreads();
#pragma unroll
    for (int p = 0; p < 4; ++p) {  // K tile: 64 rows x 128 d
      int r = p * 16 + krow_s;
      int gch = kch_s ^ (r & 7);
      const bf16* gsrc = qkv + (size_t)(b * NSEQ + kt * 64 + r) * QKV + 2048 + h * 128 + gch * 8;
      async_load16(gsrc, kdst + p * 2048);
    }
#pragma unroll
    for (int p = 0; p < 4; ++p) {  // V tile: 128 d-rows x 64 tok
      int r = p * 32 + vrow_s;
      int gch = vch_s ^ (r & 7);
      const bf16* gsrc = vt + ((size_t)b * E + h * 128 + r) * NSEQ + kt * 64 + gch * 8;
      async_load16(gsrc, vdst + p * 2048);
    }
    __syncthreads();

    if (kt > diag) continue;  // fully-masked tile for this wave (barriers already done)

    // ---- S^T = K * Q^T : two 32x32 tiles (tok x q) ----
    f32x16 st[2];
#pragma unroll
    for (int mt = 0; mt < 2; ++mt)
#pragma unroll
      for (int r = 0; r < 16; ++r) st[mt][r] = 0.f;
#pragma unroll
    for (int k8 = 0; k8 < 8; ++k8) {
#pragma unroll
      for (int mt = 0; mt < 2; ++mt) {
        int row = mt * 32 + l31;
        int sl = (k8 * 2 + half) ^ (row & 7);
        bf16x8 kf = *(const bf16x8*)(Ks + row * 128 + sl * 8);
        st[mt] = MFMA32(kf, qf[k8], st[mt]);
      }
    }

    // causal mask (diagonal tile only); C row = (r&3)+8*(r>>2)+4*half
    if (kt == diag) {
#pragma unroll
      for (int mt = 0; mt < 2; ++mt)
#pragma unroll
        for (int r = 0; r < 16; ++r) {
          int t = kt * 64 + mt * 32 + (r & 3) + 8 * (r >> 2) + 4 * half;
          if (t > qrow) st[mt][r] = -3.0e38f;
        }
    }

    // ---- online softmax: in-lane + one cross-half shuffle ----
    float mx = -3.0e38f;
#pragma unroll
    for (int mt = 0; mt < 2; ++mt)
#pragma unroll
      for (int r = 0; r < 16; ++r) mx = fmaxf(mx, st[mt][r]);
    mx = fmaxf(mx, __shfl_xor(mx, 32));
    float mnew = fmaxf(m, mx);
    float alpha = exp2f((m - mnew) * c1);
    float mc = mnew * c1;
    m = mnew;

    float psum = 0.f;
    unsigned pown[2][4][2];  // packed bf16 pairs: [mt][quad qd=r>>2][pair]
#pragma unroll
    for (int mt = 0; mt < 2; ++mt)
#pragma unroll
      for (int qd = 0; qd < 4; ++qd)
#pragma unroll
        for (int pr = 0; pr < 2; ++pr) {
          float p0 = exp2f(st[mt][qd * 4 + pr * 2] * c1 - mc);
          float p1 = exp2f(st[mt][qd * 4 + pr * 2 + 1] * c1 - mc);
          psum += p0 + p1;
          PU a; a.h[0] = (bf16)p0; a.h[1] = (bf16)p1;
          pown[mt][qd][pr] = a.u;
        }
    psum += __shfl_xor(psum, 32);
    l = l * alpha + psum;

#pragma unroll
    for (int md = 0; md < 4; ++md)
#pragma unroll
      for (int r = 0; r < 16; ++r) accO[md][r] *= alpha;

    // ---- O^T += V^T * P^T ; P fragments built by half-wave exchange ----
    // frag kk=2mt+c: h=0 -> [own qd(2c), recv qd(2c)]; h=1 -> [recv qd(2c+1), own qd(2c+1)]
#pragma unroll
    for (int mt = 0; mt < 2; ++mt)
#pragma unroll
      for (int c = 0; c < 2; ++c) {
        const int qa = 2 * c, qb = 2 * c + 1;
        unsigned ra0 = __shfl_xor(pown[mt][qa][0], 32);
        unsigned ra1 = __shfl_xor(pown[mt][qa][1], 32);
        unsigned rb0 = __shfl_xor(pown[mt][qb][0], 32);
        unsigned rb1 = __shfl_xor(pown[mt][qb][1], 32);
        FU f;
        f.u[0] = half ? rb0 : pown[mt][qa][0];
        f.u[1] = half ? rb1 : pown[mt][qa][1];
        f.u[2] = half ? pown[mt][qb][0] : ra0;
        f.u[3] = half ? pown[mt][qb][1] : ra1;
        const int kk = mt * 2 + c;
#pragma unroll
        for (int md = 0; md < 4; ++md) {
          int row = md * 32 + l31;
          bf16x8 vf = *(const bf16x8*)(Vs + row * 64 + (((kk * 2 + half) ^ (row & 7)) * 8));
          accO[md] = MFMA32(vf, f.v, accO[md]);
        }
      }
  }

  // ---- normalize, write y[b, q, h*128 + d] ----
  float invl = 1.0f / l;
  bf16* yp = yb + (size_t)(b * NSEQ + qrow) * E + h * 128;
#pragma unroll
  for (int md = 0; md < 4; ++md)
#pragma unroll
    for (int rq = 0; rq < 4; ++rq) {
      bf16x4 o;
#pragma unroll
      for (int i = 0; i < 4; ++i) o[i] = (bf16)(accO[md][rq * 4 + i] * invl);
      *(bf16x4*)(yp + md * 32 + rq * 8 + half * 4) = o;
    }
}

// ---------------- launch ----------------
extern "C" void kernel_launch(void* const* d_in, const int* in_sizes, int n_in,
                              void* d_out, int out_size, void* d_ws, size_t ws_size,
                              hipStream_t stream) {
  const float* x    = (const float*)d_in[0];
  const float* Wq   = (const float*)d_in[1];
  const float* Wkv  = (const float*)d_in[2];
  const float* Wout = (const float*)d_in[3];
  float* out = (float*)d_out;

  constexpr size_t NX = (size_t)2 * 2048 * 2048;  // 8388608
  constexpr size_t NW = (size_t)2048 * 2048;      // 4194304

  bf16* xb     = (bf16*)d_ws;
  bf16* wqkvb  = xb + NX;          // [6144 x 2048] = Wq rows then Wkv rows
  bf16* woutb  = wqkvb + 3 * NW;
  bf16* qkv_b  = woutb + NW;       // [4096 x 6144]: q | k | v per row
  bf16* y_b    = qkv_b + 3 * NX;
  bf16* vt_b   = xb;               // alias: xb dead after qkv GEMM

  cast_all_kernel<<<12288, 256, 0, stream>>>(x, Wq, Wkv, Wout, xb, wqkvb, woutb);

  // qkv = x @ [Wq; Wkv]^T : [4096, 6144]
  gemm_bt_kernel<bf16><<<dim3(48, 32), 256, 0, stream>>>(xb, wqkvb, qkv_b, 2048, 6144);
  // V cols of qkv -> Vt [b, f, n] (overwrites xb)
  vtrans_kernel<<<dim3(32, 32, 2), 256, 0, stream>>>(qkv_b, vt_b);
  // attention -> y [4096, 2048] bf16
  attn_kernel<<<dim3(32, 16), 256, 0, stream>>>(qkv_b, vt_b, y_b);
  // out = y @ Wout^T : fp32
  gemm_bt_kernel<float><<<dim3(16, 32), 256, 0, stream>>>(y_b, woutb, out, 2048, 2048);
}